// Round 3
// baseline (179.646 us; speedup 1.0000x reference)
//
#include <hip/hip_runtime.h>

#define MDIM 2048
#define NDIM 4096
#define KDIM 4096

typedef __bf16 bf16x8 __attribute__((ext_vector_type(8)));
typedef float f32x4 __attribute__((ext_vector_type(4)));

// CK-style addrspace cast idiom (flat LDS addr low 32 bits == LDS offset on gfx9+)
__device__ inline void load_lds16(const void* gptr, void* lptr) {
    auto g1 = reinterpret_cast<const __attribute__((address_space(1))) unsigned int*>(
        reinterpret_cast<uintptr_t>(gptr));
    auto l3 = reinterpret_cast<__attribute__((address_space(3))) unsigned int*>(
        reinterpret_cast<uintptr_t>(lptr));
    __builtin_amdgcn_global_load_lds(g1, l3, 16, 0, 0);
}

// ---------------------------------------------------------------------------
// Prologue (one dispatch, 1536 blocks) — UNCHANGED:
//   blocks 0..1023  : BCQ dequant -> WT bf16 [N,K]  (LDS-transpose tile)
//   blocks 1024..1535: x fp32 -> bf16 Xb [M,K]
// ---------------------------------------------------------------------------
__global__ __launch_bounds__(256) void prologue_kernel(
    const float* __restrict__ x,      // [M, K] fp32
    const int* __restrict__ binary,   // [K/32, 4, N]
    const float* __restrict__ alpha,  // [K/128, 4, N]
    const float* __restrict__ q_bias, // [K/128, N]
    __bf16* __restrict__ WT,          // [N, K]
    __bf16* __restrict__ Xb)          // [M, K]
{
    __shared__ __align__(16) unsigned Ls[64 * 132];   // 64 rows x 33 granules

    const int t = threadIdx.x;
    const int bid = blockIdx.x;

    if (bid < 1024) {
        const int n0 = (bid & 63) * 64;
        const int k32_0 = (bid >> 6) * 8;
        const int n_l = t & 63;            // lane -> n (coalesced global reads)
        const int k_l = t >> 6;            // wave id 0..3
        const int n = n0 + n_l;

        uint4* L4 = reinterpret_cast<uint4*>(Ls);

#pragma unroll
        for (int c = 0; c < 2; ++c) {
            const int k32 = k32_0 + k_l * 2 + c;
            const int g = k32 >> 2;

            const unsigned w0 = (unsigned)binary[(k32 * 4 + 0) * NDIM + n];
            const unsigned w1 = (unsigned)binary[(k32 * 4 + 1) * NDIM + n];
            const unsigned w2 = (unsigned)binary[(k32 * 4 + 2) * NDIM + n];
            const unsigned w3 = (unsigned)binary[(k32 * 4 + 3) * NDIM + n];
            const float a0 = alpha[(g * 4 + 0) * NDIM + n];
            const float a1 = alpha[(g * 4 + 1) * NDIM + n];
            const float a2 = alpha[(g * 4 + 2) * NDIM + n];
            const float a3 = alpha[(g * 4 + 3) * NDIM + n];
            const float qb = q_bias[g * NDIM + n];

            const int cellg = (k_l * 2 + c) * 4;
#pragma unroll
            for (int j = 0; j < 4; ++j) {                  // granule = 8 weights
                unsigned pk[4];
#pragma unroll
                for (int h = 0; h < 4; ++h) {
                    const int i0 = j * 8 + h * 2;
                    float v0 = qb, v1 = qb;
                    v0 += ((w0 >> i0) & 1u) ? a0 : -a0;
                    v0 += ((w1 >> i0) & 1u) ? a1 : -a1;
                    v0 += ((w2 >> i0) & 1u) ? a2 : -a2;
                    v0 += ((w3 >> i0) & 1u) ? a3 : -a3;
                    const int i1 = i0 + 1;
                    v1 += ((w0 >> i1) & 1u) ? a0 : -a0;
                    v1 += ((w1 >> i1) & 1u) ? a1 : -a1;
                    v1 += ((w2 >> i1) & 1u) ? a2 : -a2;
                    v1 += ((w3 >> i1) & 1u) ? a3 : -a3;
                    const unsigned lo = __builtin_bit_cast(unsigned short, (__bf16)v0);
                    const unsigned hi = __builtin_bit_cast(unsigned short, (__bf16)v1);
                    pk[h] = lo | (hi << 16);
                }
                uint4 q;
                q.x = pk[0]; q.y = pk[1]; q.z = pk[2]; q.w = pk[3];
                L4[n_l * 33 + cellg + j] = q;
            }
        }

        __syncthreads();

        uint4* dstv = reinterpret_cast<uint4*>(WT);
        const int kcol0 = (bid >> 6) * 32;
#pragma unroll
        for (int p = 0; p < 8; ++p) {
            const int idx = p * 256 + t;
            const int row = idx >> 5;
            const int gI = idx & 31;
            const uint4 q = L4[row * 33 + gI];
            dstv[(size_t)(n0 + row) * (KDIM / 8) + kcol0 + gI] = q;
        }
    } else {
        const int cb = bid - 1024;         // 0..511
#pragma unroll
        for (int i = 0; i < 8; ++i) {
            const int id = cb * 2048 + i * 256 + t;
            const float4* xv = reinterpret_cast<const float4*>(x) + (size_t)id * 2;
            const float4 v0 = xv[0];
            const float4 v1 = xv[1];
            union { __bf16 h[8]; uint4 q; } u;
            u.h[0] = (__bf16)v0.x; u.h[1] = (__bf16)v0.y;
            u.h[2] = (__bf16)v0.z; u.h[3] = (__bf16)v0.w;
            u.h[4] = (__bf16)v1.x; u.h[5] = (__bf16)v1.y;
            u.h[6] = (__bf16)v1.z; u.h[7] = (__bf16)v1.w;
            reinterpret_cast<uint4*>(Xb)[id] = u.q;
        }
    }
}

// ---------------------------------------------------------------------------
// GEMM v5: 128x64 wave tiles (reads/MFMA 0.375 vs 0.5) to cut the LDS-read
// floor. Block 256x128, 4 waves (2M x 2N), grid 8x32 = 256 = 1 block/CU.
// LDS reads/iter: A 32KB x2 + B 16KB x2 = 96KB (was 128KB); MFMA 1242 cyc
// ~= LDS ~1285 cyc -> balanced floor ~34-45us. 1 wave/SIMD: latency hiding is
// pure ILP (m114: single wave saturates the MFMA pipe; phase-shifted frag
// reads + 2-ahead staging provide the independent work).
// Pipeline structure identical to verified v4: ONE raw s_barrier + ONE
// counted vmcnt per K-iter, triple-buffered LDS, staging 2 tiles ahead
// (12 loads/tile -> steady-state wait vmcnt(12)). Same XOR granule swizzle
// (fragment pattern unchanged), same K-order -> identical numerics.
// ---------------------------------------------------------------------------
__global__ __launch_bounds__(256, 1) void gemm_kernel(
    const __bf16* __restrict__ A,   // [M, K]
    const __bf16* __restrict__ BT,  // [N, K]
    const float* __restrict__ bias, // [N]
    float* __restrict__ C)          // [M, N]
{
    constexpr int BM = 256, BN = 128, BK = 64;
    constexpr int NITER = KDIM / BK;                 // 64
    __shared__ __align__(16) __bf16 As[3][BM * BK];  // 3 x 32 KB
    __shared__ __align__(16) __bf16 Bs[3][BN * BK];  // 3 x 16 KB

    const int t = threadIdx.x;
    const int lane = t & 63;
    const int wave = t >> 6;          // 0..3
    const int wr = wave >> 1;         // 0..1 -> M offset wr*128
    const int wc = wave & 1;          // 0..1 -> N offset wc*64
    const int bm = blockIdx.x * BM;   // grid.x = 8
    const int bn = blockIdx.y * BN;   // grid.y = 32

    // Staging maps: LDS dest lane-linear (gload_lds requirement); granule XOR
    // swizzle pre-applied on the GLOBAL source address.
    int a_goff[8], a_slot[8];
#pragma unroll
    for (int r = 0; r < 8; ++r) {
        const int s = r * 256 + t;            // A: 256 rows * 8 granules = 2048
        const int m = s >> 3;
        const int g = (s & 7) ^ (m & 7);
        a_slot[r] = s * 8;
        a_goff[r] = (bm + m) * KDIM + g * 8;
    }
    int b_goff[4], b_slot[4];
#pragma unroll
    for (int r = 0; r < 4; ++r) {
        const int s = r * 256 + t;            // B: 128 rows * 8 granules = 1024
        const int n = s >> 3;
        const int g = (s & 7) ^ (n & 7);
        b_slot[r] = s * 8;
        b_goff[r] = (bn + n) * KDIM + g * 8;
    }

    const int r16 = lane & 15;
    const int kq = lane >> 4;                 // 0..3
    const int X = r16 & 7;                    // (row & 7) for A and B frags
    const int aBase = (wr * 128 + r16) * 8;
    const int bBase = (wc * 64 + r16) * 8;

    f32x4 acc[8][4];
#pragma unroll
    for (int i = 0; i < 8; ++i)
#pragma unroll
        for (int j = 0; j < 4; ++j)
            acc[i][j] = f32x4{0.f, 0.f, 0.f, 0.f};

    // Prologue: stage tile 0 -> buf0, tile 1 -> buf1 (12 loads each).
#pragma unroll
    for (int r = 0; r < 8; ++r) load_lds16(A + a_goff[r], &As[0][a_slot[r]]);
#pragma unroll
    for (int r = 0; r < 4; ++r) load_lds16(BT + b_goff[r], &Bs[0][b_slot[r]]);
#pragma unroll
    for (int r = 0; r < 8; ++r) load_lds16(A + a_goff[r] + BK, &As[1][a_slot[r]]);
#pragma unroll
    for (int r = 0; r < 4; ++r) load_lds16(BT + b_goff[r] + BK, &Bs[1][b_slot[r]]);
    asm volatile("s_waitcnt vmcnt(12)" ::: "memory");  // tile 0 landed (pre-barrier)
    __builtin_amdgcn_s_barrier();

    // Preload ks=0 fragments of tile 0.
    bf16x8 af0[8], bf0[4], af1[8], bf1[4];
    {
        const bf16x8* Av = reinterpret_cast<const bf16x8*>(&As[0][0]);
        const bf16x8* Bv = reinterpret_cast<const bf16x8*>(&Bs[0][0]);
#pragma unroll
        for (int mi = 0; mi < 8; ++mi) af0[mi] = Av[aBase + mi * 128 + (kq ^ X)];
#pragma unroll
        for (int ni = 0; ni < 4; ++ni) bf0[ni] = Bv[bBase + ni * 128 + (kq ^ X)];
    }

    int rb = 0;          // buffer holding tile `it`
    for (int it = 0; it < NITER; ++it) {
        const bool st = (it + 2 < NITER);
        const int rb1 = (rb == 2) ? 0 : rb + 1;   // buffer of tile it+1
        const int sb  = (rb == 0) ? 2 : rb - 1;   // (rb+2)%3: stage target (tile it+2)
        const bf16x8* Av = reinterpret_cast<const bf16x8*>(&As[rb][0]);
        const bf16x8* Bv = reinterpret_cast<const bf16x8*>(&Bs[rb][0]);

        // Issue next-next tile's staging (WAR-safe: slot's last reads were
        // issued before the previous iter's barrier; glds data arrival is
        // >= 1 barrier + >=200cyc VMEM latency later).
        if (st) {
            const int kt = (it + 2) * BK;
#pragma unroll
            for (int r = 0; r < 8; ++r)
                load_lds16(A + a_goff[r] + kt, &As[sb][a_slot[r]]);
#pragma unroll
            for (int r = 0; r < 4; ++r)
                load_lds16(BT + b_goff[r] + kt, &Bs[sb][b_slot[r]]);
        }

        // Reads for the ks=1 cluster (tile it) — independent of MFMA ks=0.
#pragma unroll
        for (int mi = 0; mi < 8; ++mi) af1[mi] = Av[aBase + mi * 128 + ((4 + kq) ^ X)];
#pragma unroll
        for (int ni = 0; ni < 4; ++ni) bf1[ni] = Bv[bBase + ni * 128 + ((4 + kq) ^ X)];

#pragma unroll
        for (int mi = 0; mi < 8; ++mi)
#pragma unroll
            for (int ni = 0; ni < 4; ++ni)
                acc[mi][ni] = __builtin_amdgcn_mfma_f32_16x16x32_bf16(
                    af0[mi], bf0[ni], acc[mi][ni], 0, 0, 0);

        // Boundary: tile it+1 must be landed for ALL waves before anyone
        // reads it: per-wave counted wait (own 12 loads), THEN barrier.
        if (st) asm volatile("s_waitcnt vmcnt(12)" ::: "memory");
        else    asm volatile("s_waitcnt vmcnt(0)" ::: "memory");  // drain tail
        __builtin_amdgcn_s_barrier();

        // Reads for next iter's ks=0 cluster (tile it+1) — overlap MFMA ks=1.
        if (it + 1 < NITER) {
            const bf16x8* Av1 = reinterpret_cast<const bf16x8*>(&As[rb1][0]);
            const bf16x8* Bv1 = reinterpret_cast<const bf16x8*>(&Bs[rb1][0]);
#pragma unroll
            for (int mi = 0; mi < 8; ++mi) af0[mi] = Av1[aBase + mi * 128 + (kq ^ X)];
#pragma unroll
            for (int ni = 0; ni < 4; ++ni) bf0[ni] = Bv1[bBase + ni * 128 + (kq ^ X)];
        }

#pragma unroll
        for (int mi = 0; mi < 8; ++mi)
#pragma unroll
            for (int ni = 0; ni < 4; ++ni)
                acc[mi][ni] = __builtin_amdgcn_mfma_f32_16x16x32_bf16(
                    af1[mi], bf1[ni], acc[mi][ni], 0, 0, 0);

        rb = rb1;
    }

    // Epilogue: C/D layout col = lane&15, row = kq*4 + reg.
    float bv[4];
#pragma unroll
    for (int ni = 0; ni < 4; ++ni)
        bv[ni] = bias[bn + wc * 64 + ni * 16 + r16];

    const int row0 = bm + wr * 128 + kq * 4;
    const int col0 = bn + wc * 64 + r16;
#pragma unroll
    for (int mi = 0; mi < 8; ++mi) {
#pragma unroll
        for (int rr = 0; rr < 4; ++rr) {
            float* crow = C + (size_t)(row0 + mi * 16 + rr) * NDIM + col0;
#pragma unroll
            for (int ni = 0; ni < 4; ++ni)
                crow[ni * 16] = acc[mi][ni][rr] + bv[ni];
        }
    }
}

extern "C" void kernel_launch(void* const* d_in, const int* in_sizes, int n_in,
                              void* d_out, int out_size, void* d_ws, size_t ws_size,
                              hipStream_t stream) {
    const float* x      = (const float*)d_in[0];   // [1, 2048, 4096]
    const int*   binary = (const int*)d_in[1];     // [128, 4, 4096]
    const float* alpha  = (const float*)d_in[2];   // [32, 4, 4096]
    const float* q_bias = (const float*)d_in[3];   // [32, 4096]
    const float* bias   = (const float*)d_in[4];   // [4096]
    float* out = (float*)d_out;                    // [1, 2048, 4096] fp32

    __bf16* WT = (__bf16*)d_ws;                        // 32 MB
    __bf16* Xb = WT + (size_t)NDIM * KDIM;             // 16 MB

    prologue_kernel<<<1536, 256, 0, stream>>>(x, binary, alpha, q_bias, WT, Xb);

    dim3 grid(MDIM / 256, NDIM / 128);
    gemm_kernel<<<grid, 256, 0, stream>>>(Xb, WT, bias, out);
}

// Round 4
// 163.787 us; speedup vs baseline: 1.0968x; 1.0968x over previous
//
#include <hip/hip_runtime.h>

#define MDIM 2048
#define NDIM 4096
#define KDIM 4096

typedef __bf16 bf16x8 __attribute__((ext_vector_type(8)));
typedef float f32x4 __attribute__((ext_vector_type(4)));

// CK-style addrspace cast idiom (flat LDS addr low 32 bits == LDS offset on gfx9+)
__device__ inline void load_lds16(const void* gptr, void* lptr) {
    auto g1 = reinterpret_cast<const __attribute__((address_space(1))) unsigned int*>(
        reinterpret_cast<uintptr_t>(gptr));
    auto l3 = reinterpret_cast<__attribute__((address_space(3))) unsigned int*>(
        reinterpret_cast<uintptr_t>(lptr));
    __builtin_amdgcn_global_load_lds(g1, l3, 16, 0, 0);
}

// ---------------------------------------------------------------------------
// Prologue (one dispatch, 1536 blocks) — UNCHANGED (~4 us, L3-resident):
//   blocks 0..1023  : BCQ dequant -> WT bf16 [N,K]  (LDS-transpose tile)
//   blocks 1024..1535: x fp32 -> bf16 Xb [M,K]
// ---------------------------------------------------------------------------
__global__ __launch_bounds__(256) void prologue_kernel(
    const float* __restrict__ x,      // [M, K] fp32
    const int* __restrict__ binary,   // [K/32, 4, N]
    const float* __restrict__ alpha,  // [K/128, 4, N]
    const float* __restrict__ q_bias, // [K/128, N]
    __bf16* __restrict__ WT,          // [N, K]
    __bf16* __restrict__ Xb)          // [M, K]
{
    __shared__ __align__(16) unsigned Ls[64 * 132];   // 64 rows x 33 granules

    const int t = threadIdx.x;
    const int bid = blockIdx.x;

    if (bid < 1024) {
        const int n0 = (bid & 63) * 64;
        const int k32_0 = (bid >> 6) * 8;
        const int n_l = t & 63;            // lane -> n (coalesced global reads)
        const int k_l = t >> 6;            // wave id 0..3
        const int n = n0 + n_l;

        uint4* L4 = reinterpret_cast<uint4*>(Ls);

#pragma unroll
        for (int c = 0; c < 2; ++c) {
            const int k32 = k32_0 + k_l * 2 + c;
            const int g = k32 >> 2;

            const unsigned w0 = (unsigned)binary[(k32 * 4 + 0) * NDIM + n];
            const unsigned w1 = (unsigned)binary[(k32 * 4 + 1) * NDIM + n];
            const unsigned w2 = (unsigned)binary[(k32 * 4 + 2) * NDIM + n];
            const unsigned w3 = (unsigned)binary[(k32 * 4 + 3) * NDIM + n];
            const float a0 = alpha[(g * 4 + 0) * NDIM + n];
            const float a1 = alpha[(g * 4 + 1) * NDIM + n];
            const float a2 = alpha[(g * 4 + 2) * NDIM + n];
            const float a3 = alpha[(g * 4 + 3) * NDIM + n];
            const float qb = q_bias[g * NDIM + n];

            const int cellg = (k_l * 2 + c) * 4;
#pragma unroll
            for (int j = 0; j < 4; ++j) {                  // granule = 8 weights
                unsigned pk[4];
#pragma unroll
                for (int h = 0; h < 4; ++h) {
                    const int i0 = j * 8 + h * 2;
                    float v0 = qb, v1 = qb;
                    v0 += ((w0 >> i0) & 1u) ? a0 : -a0;
                    v0 += ((w1 >> i0) & 1u) ? a1 : -a1;
                    v0 += ((w2 >> i0) & 1u) ? a2 : -a2;
                    v0 += ((w3 >> i0) & 1u) ? a3 : -a3;
                    const int i1 = i0 + 1;
                    v1 += ((w0 >> i1) & 1u) ? a0 : -a0;
                    v1 += ((w1 >> i1) & 1u) ? a1 : -a1;
                    v1 += ((w2 >> i1) & 1u) ? a2 : -a2;
                    v1 += ((w3 >> i1) & 1u) ? a3 : -a3;
                    const unsigned lo = __builtin_bit_cast(unsigned short, (__bf16)v0);
                    const unsigned hi = __builtin_bit_cast(unsigned short, (__bf16)v1);
                    pk[h] = lo | (hi << 16);
                }
                uint4 q;
                q.x = pk[0]; q.y = pk[1]; q.z = pk[2]; q.w = pk[3];
                L4[n_l * 33 + cellg + j] = q;
            }
        }

        __syncthreads();

        uint4* dstv = reinterpret_cast<uint4*>(WT);
        const int kcol0 = (bid >> 6) * 32;
#pragma unroll
        for (int p = 0; p < 8; ++p) {
            const int idx = p * 256 + t;
            const int row = idx >> 5;
            const int gI = idx & 31;
            const uint4 q = L4[row * 33 + gI];
            dstv[(size_t)(n0 + row) * (KDIM / 8) + kcol0 + gI] = q;
        }
    } else {
        const int cb = bid - 1024;         // 0..511
#pragma unroll
        for (int i = 0; i < 8; ++i) {
            const int id = cb * 2048 + i * 256 + t;
            const float4* xv = reinterpret_cast<const float4*>(x) + (size_t)id * 2;
            const float4 v0 = xv[0];
            const float4 v1 = xv[1];
            union { __bf16 h[8]; uint4 q; } u;
            u.h[0] = (__bf16)v0.x; u.h[1] = (__bf16)v0.y;
            u.h[2] = (__bf16)v0.z; u.h[3] = (__bf16)v0.w;
            u.h[4] = (__bf16)v1.x; u.h[5] = (__bf16)v1.y;
            u.h[6] = (__bf16)v1.z; u.h[7] = (__bf16)v1.w;
            reinterpret_cast<uint4*>(Xb)[id] = u.q;
        }
    }
}

// ---------------------------------------------------------------------------
// GEMM v4 (reverted from v5 — R3 post-mortem: 128x64 wave tiles at 1 wave/SIMD
// lost all TLP, 68.5 -> 105 us despite the better LDS-read ratio).
// Phase-shifted register pipeline, ONE raw s_barrier + ONE counted vmcnt per
// K-iter. Triple-buffered LDS, staging 2 tiles ahead (vmcnt(6) steady-state
// slack = 1 full K-iter). Fragment reads for the NEXT MFMA cluster sit in the
// same scheduling region as an independent MFMA cluster, so the compiler's
// fine-grained lgkmcnt pipelining overlaps LDS-read service with MFMA.
// Measured: 68.5 us profiled (1003 TF), MfmaUtil 42%, bank conflicts 0.
// ---------------------------------------------------------------------------
__global__ __launch_bounds__(512, 2) void gemm_kernel(
    const __bf16* __restrict__ A,   // [M, K]
    const __bf16* __restrict__ BT,  // [N, K]
    const float* __restrict__ bias, // [N]
    float* __restrict__ C)          // [M, N]
{
    constexpr int BM = 128, BN = 256, BK = 64;
    constexpr int NITER = KDIM / BK;                 // 64
    __shared__ __align__(16) __bf16 As[3][BM * BK];  // 3 x 16 KB
    __shared__ __align__(16) __bf16 Bs[3][BN * BK];  // 3 x 32 KB

    const int t = threadIdx.x;
    const int lane = t & 63;
    const int wave = t >> 6;          // 0..7
    const int wr = wave >> 2;         // 0..1  -> M offset wr*64
    const int wc = wave & 3;          // 0..3  -> N offset wc*64
    const int bm = blockIdx.x * BM;
    const int bn = blockIdx.y * BN;

    // Staging maps: LDS dest is lane-linear (gload_lds requirement); the
    // granule XOR swizzle is pre-applied on the GLOBAL source address.
    int a_goff[2], a_slot[2];
#pragma unroll
    for (int r = 0; r < 2; ++r) {
        const int s = r * 512 + t;            // A: 128 rows * 8 granules
        const int m = s >> 3;
        const int g = (s & 7) ^ (m & 7);
        a_slot[r] = s * 8;
        a_goff[r] = (bm + m) * KDIM + g * 8;
    }
    int b_goff[4], b_slot[4];
#pragma unroll
    for (int r = 0; r < 4; ++r) {
        const int s = r * 512 + t;            // B: 256 rows * 8 granules
        const int n = s >> 3;
        const int g = (s & 7) ^ (n & 7);
        b_slot[r] = s * 8;
        b_goff[r] = (bn + n) * KDIM + g * 8;
    }

    const int r16 = lane & 15;
    const int kq = lane >> 4;                 // 0..3
    const int X = r16 & 7;                    // (row & 7) for A and B frags
    const int aBase = (wr * 64 + r16) * 8;
    const int bBase = (wc * 64 + r16) * 8;

    f32x4 acc[4][4];
#pragma unroll
    for (int i = 0; i < 4; ++i)
#pragma unroll
        for (int j = 0; j < 4; ++j)
            acc[i][j] = f32x4{0.f, 0.f, 0.f, 0.f};

    // Prologue: stage tile 0 -> buf0, tile 1 -> buf1 (6 loads each).
#pragma unroll
    for (int r = 0; r < 2; ++r) load_lds16(A + a_goff[r], &As[0][a_slot[r]]);
#pragma unroll
    for (int r = 0; r < 4; ++r) load_lds16(BT + b_goff[r], &Bs[0][b_slot[r]]);
#pragma unroll
    for (int r = 0; r < 2; ++r) load_lds16(A + a_goff[r] + BK, &As[1][a_slot[r]]);
#pragma unroll
    for (int r = 0; r < 4; ++r) load_lds16(BT + b_goff[r] + BK, &Bs[1][b_slot[r]]);
    asm volatile("s_waitcnt vmcnt(6)" ::: "memory");  // tile 0 landed (all waves pre-barrier)
    __builtin_amdgcn_s_barrier();

    // Preload ks=0 fragments of tile 0.
    bf16x8 af0[4], bf0[4], af1[4], bf1[4];
    {
        const bf16x8* Av = reinterpret_cast<const bf16x8*>(&As[0][0]);
        const bf16x8* Bv = reinterpret_cast<const bf16x8*>(&Bs[0][0]);
#pragma unroll
        for (int mi = 0; mi < 4; ++mi) af0[mi] = Av[aBase + mi * 128 + (kq ^ X)];
#pragma unroll
        for (int ni = 0; ni < 4; ++ni) bf0[ni] = Bv[bBase + ni * 128 + (kq ^ X)];
    }

    int rb = 0;          // buffer holding tile `it`
    for (int it = 0; it < NITER; ++it) {
        const bool st = (it + 2 < NITER);
        const int rb1 = (rb == 2) ? 0 : rb + 1;   // buffer of tile it+1
        const int sb  = (rb == 0) ? 2 : rb - 1;   // (rb+2)%3: stage target (tile it+2)
        const bf16x8* Av = reinterpret_cast<const bf16x8*>(&As[rb][0]);
        const bf16x8* Bv = reinterpret_cast<const bf16x8*>(&Bs[rb][0]);

        // Issue next-next tile's staging (lands >= 1 full iter later; slot's
        // last reads were >= 1 barrier + glds-latency ago -> WAR-safe).
        if (st) {
            const int kt = (it + 2) * BK;
            load_lds16(A + a_goff[0] + kt, &As[sb][a_slot[0]]);
            load_lds16(A + a_goff[1] + kt, &As[sb][a_slot[1]]);
            load_lds16(BT + b_goff[0] + kt, &Bs[sb][b_slot[0]]);
            load_lds16(BT + b_goff[1] + kt, &Bs[sb][b_slot[1]]);
            load_lds16(BT + b_goff[2] + kt, &Bs[sb][b_slot[2]]);
            load_lds16(BT + b_goff[3] + kt, &Bs[sb][b_slot[3]]);
        }

        // Reads for the ks=1 cluster (tile it) — independent of MFMA ks=0:
        // compiler interleaves them under counted lgkmcnt.
#pragma unroll
        for (int mi = 0; mi < 4; ++mi) af1[mi] = Av[aBase + mi * 128 + ((4 + kq) ^ X)];
#pragma unroll
        for (int ni = 0; ni < 4; ++ni) bf1[ni] = Bv[bBase + ni * 128 + ((4 + kq) ^ X)];

        __builtin_amdgcn_s_setprio(1);
#pragma unroll
        for (int mi = 0; mi < 4; ++mi)
#pragma unroll
            for (int ni = 0; ni < 4; ++ni)
                acc[mi][ni] = __builtin_amdgcn_mfma_f32_16x16x32_bf16(
                    af0[mi], bf0[ni], acc[mi][ni], 0, 0, 0);
        __builtin_amdgcn_s_setprio(0);

        // Boundary: tile it+1 (staged during it-1) must be fully landed for
        // ALL waves before anyone reads it: per-wave counted wait, THEN
        // barrier. Outstanding after wait = this iter's 6 loads (tile it+2).
        if (st) asm volatile("s_waitcnt vmcnt(6)" ::: "memory");
        else    asm volatile("s_waitcnt vmcnt(0)" ::: "memory");  // drain tail
        __builtin_amdgcn_s_barrier();

        // Reads for next iter's ks=0 cluster (tile it+1) — overlap MFMA ks=1.
        if (it + 1 < NITER) {
            const bf16x8* Av1 = reinterpret_cast<const bf16x8*>(&As[rb1][0]);
            const bf16x8* Bv1 = reinterpret_cast<const bf16x8*>(&Bs[rb1][0]);
#pragma unroll
            for (int mi = 0; mi < 4; ++mi) af0[mi] = Av1[aBase + mi * 128 + (kq ^ X)];
#pragma unroll
            for (int ni = 0; ni < 4; ++ni) bf0[ni] = Bv1[bBase + ni * 128 + (kq ^ X)];
        }

        __builtin_amdgcn_s_setprio(1);
#pragma unroll
        for (int mi = 0; mi < 4; ++mi)
#pragma unroll
            for (int ni = 0; ni < 4; ++ni)
                acc[mi][ni] = __builtin_amdgcn_mfma_f32_16x16x32_bf16(
                    af1[mi], bf1[ni], acc[mi][ni], 0, 0, 0);
        __builtin_amdgcn_s_setprio(0);

        rb = rb1;
    }

    // Epilogue: C/D layout col = lane&15, row = kq*4 + reg.
    float bv[4];
#pragma unroll
    for (int ni = 0; ni < 4; ++ni)
        bv[ni] = bias[bn + wc * 64 + ni * 16 + r16];

    const int row0 = bm + wr * 64 + kq * 4;
    const int col0 = bn + wc * 64 + r16;
#pragma unroll
    for (int mi = 0; mi < 4; ++mi) {
#pragma unroll
        for (int rr = 0; rr < 4; ++rr) {
            float* crow = C + (size_t)(row0 + mi * 16 + rr) * NDIM + col0;
#pragma unroll
            for (int ni = 0; ni < 4; ++ni)
                crow[ni * 16] = acc[mi][ni][rr] + bv[ni];
        }
    }
}

extern "C" void kernel_launch(void* const* d_in, const int* in_sizes, int n_in,
                              void* d_out, int out_size, void* d_ws, size_t ws_size,
                              hipStream_t stream) {
    const float* x      = (const float*)d_in[0];   // [1, 2048, 4096]
    const int*   binary = (const int*)d_in[1];     // [128, 4, 4096]
    const float* alpha  = (const float*)d_in[2];   // [32, 4, 4096]
    const float* q_bias = (const float*)d_in[3];   // [32, 4096]
    const float* bias   = (const float*)d_in[4];   // [4096]
    float* out = (float*)d_out;                    // [1, 2048, 4096] fp32

    __bf16* WT = (__bf16*)d_ws;                        // 32 MB
    __bf16* Xb = WT + (size_t)NDIM * KDIM;             // 16 MB

    prologue_kernel<<<1536, 256, 0, stream>>>(x, binary, alpha, q_bias, WT, Xb);

    dim3 grid(MDIM / 128, NDIM / 256);
    gemm_kernel<<<grid, 512, 0, stream>>>(Xb, WT, bias, out);
}